// Round 3
// baseline (247.077 us; speedup 1.0000x reference)
//
#include <hip/hip_runtime.h>

// Problem constants: B=4, R=16384, S=96
#define NRAYS 65536
#define NS    96
#define NI    95

// Output layout (FP32, outputs concatenated flat in return order):
//   composite_rgb   : [0,        196608)
//   composite_depth : [196608,   262144)
//   weights         : [262144,   6488064)
//   composite_point : [6488064,  6684672)
//   tau             : [6684672,  6750208)
#define OFF_RGB   0
#define OFF_DEPTH 196608
#define OFF_W     262144
#define OFF_PT    6488064
#define OFF_TAU   6684672

// ---------------------------------------------------------------------------
// Global depth min/max. depths are jnp.sort()ed along the sample axis by
// construction, so global min = min over rays of sample 0, global max = max
// over rays of sample 95. Max encoded as atomicMin of ~bits (depths >= 0),
// so both ws slots init 0xFFFFFFFF -> single 8-byte memset.
// ---------------------------------------------------------------------------
__global__ void depth_minmax_sorted(const float* __restrict__ deps, unsigned* ws) {
    const int t = blockIdx.x * blockDim.x + threadIdx.x;   // grid covers exactly NRAYS
    float lo = deps[(size_t)t * NS];
    float hi = deps[(size_t)t * NS + (NS - 1)];
    #pragma unroll
    for (int off = 32; off; off >>= 1) {
        lo = fminf(lo, __shfl_xor(lo, off, 64));
        hi = fmaxf(hi, __shfl_xor(hi, off, 64));
    }
    if ((threadIdx.x & 63) == 0) {
        atomicMin(&ws[0], __float_as_uint(lo));
        atomicMin(&ws[1], ~__float_as_uint(hi));   // max via inverted-bit min
    }
}

__device__ __forceinline__ float softplus_fast(float x) {
    // softplus = max(x,0) + log(1 + exp(-|x|)); __logf/__expf are single
    // v_log/v_exp instrs (~1e-6 rel err; tolerance headroom ~6x).
    return fmaxf(x, 0.0f) + __logf(1.0f + __expf(-fabsf(x)));
}

// ---------------------------------------------------------------------------
// 16 lanes per ray, 4 rays per wave, 6 samples per lane, 16 rays per block.
// R2 post-mortem: transactions fixed (LDS staging) but 36 KB LDS halved
// occupancy to ~2.8 waves/SIMD -> latency-bound, same 77 us. This version
// keeps BOTH properties: ONE 18.4 KB buffer reused 3x (colors -> coords ->
// weights), so 8 blocks/CU (32 waves/CU) AND coalesced global traffic.
// Weights are staged in LDS and stored as block-contiguous float4 (the
// block's weight range OFF_W + blk*1520 floats is 16 B-aligned), removing
// the 24-B-stride dword scatter. Value path identical to verified R1/R2.
// ---------------------------------------------------------------------------
__launch_bounds__(256, 8)
__global__ void raymarch(const float* __restrict__ colors,
                         const float* __restrict__ dens,
                         const float* __restrict__ deps,
                         const float* __restrict__ coords,
                         const int* __restrict__ wbp,
                         const unsigned* __restrict__ mm,
                         float* __restrict__ out) {
    __shared__ float sbuf[16 * 288];   // 18432 B, reused: colors, coords, weights

    const int tid  = threadIdx.x;
    const int lane = tid & 63;
    const int sub  = tid & 15;                    // position within ray group
    const int r    = tid >> 4;                    // ray within block (0..15)
    const int g    = blockIdx.x * 16 + r;         // global ray id

    // ---- direct loads (24 B lane stride, small arrays): 6 samples/lane ----
    float d[6], n[6];
    {
        const float2* q = (const float2*)(deps + (size_t)g * NS) + 3 * sub;
        #pragma unroll
        for (int j = 0; j < 3; ++j) { float2 v = q[j]; d[2*j] = v.x; d[2*j+1] = v.y; }
    }
    {
        const float2* q = (const float2*)(dens + (size_t)g * NS) + 3 * sub;
        #pragma unroll
        for (int j = 0; j < 3; ++j) { float2 v = q[j]; n[2*j] = v.x; n[2*j+1] = v.y; }
    }

    float4* s4 = (float4*)sbuf;

    // ---- phase 1: stage colors (coalesced float4), read per-lane slice ----
    {
        const float4* g1 = (const float4*)(colors + (size_t)blockIdx.x * (16 * 288));
        #pragma unroll
        for (int k = 0; k < 4; ++k) s4[tid + 256 * k] = g1[tid + 256 * k];
        if (tid < 128) s4[tid + 1024] = g1[tid + 1024];
    }
    __syncthreads();
    float c[18], cn0, cn1, cn2;
    {
        const float2* q = (const float2*)(sbuf + r * 288 + 18 * sub);
        #pragma unroll
        for (int j = 0; j < 9; ++j) { float2 v = q[j]; c[2*j] = v.x; c[2*j+1] = v.y; }
        const int noff = (sub < 15) ? 18 * (sub + 1) : 0;   // dummy for sub 15
        cn0 = sbuf[r * 288 + noff + 0];
        cn1 = sbuf[r * 288 + noff + 1];
        cn2 = sbuf[r * 288 + noff + 2];
    }
    __syncthreads();

    // ---- phase 2: stage coords into the SAME buffer, read slice ----
    {
        const float4* g2 = (const float4*)(coords + (size_t)blockIdx.x * (16 * 288));
        #pragma unroll
        for (int k = 0; k < 4; ++k) s4[tid + 256 * k] = g2[tid + 256 * k];
        if (tid < 128) s4[tid + 1024] = g2[tid + 1024];
    }
    __syncthreads();
    float p[18], pn0, pn1, pn2;
    {
        const float2* q = (const float2*)(sbuf + r * 288 + 18 * sub);
        #pragma unroll
        for (int j = 0; j < 9; ++j) { float2 v = q[j]; p[2*j] = v.x; p[2*j+1] = v.y; }
        const int noff = (sub < 15) ? 18 * (sub + 1) : 0;
        pn0 = sbuf[r * 288 + noff + 0];
        pn1 = sbuf[r * 288 + noff + 1];
        pn2 = sbuf[r * 288 + noff + 2];
    }

    // depths/densities neighbor via shuffle (not staged)
    const int nsrc = (lane & 48) | ((sub + 1) & 15);
    float d6 = __shfl(d[0], nsrc, 64);
    float n6 = __shfl(n[0], nsrc, 64);

    // ---- per-interval alpha / transmittance factor (interval 95 invalid) ----
    float a[6], f[6];
    #pragma unroll
    for (int i = 0; i < 6; ++i) {
        float dn1 = (i < 5) ? d[i+1] : d6;
        float nn1 = (i < 5) ? n[i+1] : n6;
        float E = __expf(-softplus_fast(0.5f * (n[i] + nn1)) * (dn1 - d[i]));
        const bool valid = (i < 5) || (sub < 15);    // compile-time except i==5
        a[i] = valid ? (1.0f - E) : 0.0f;
        f[i] = valid ? (E + 1e-10f) : 1.0f;
    }

    // ---- inclusive scan of per-lane factor product over the 16-lane group ----
    float incl = ((f[0] * f[1]) * (f[2] * f[3])) * (f[4] * f[5]);
    #pragma unroll
    for (int off = 1; off < 16; off <<= 1) {
        float t = __shfl_up(incl, off, 16);
        if (sub >= off) incl *= t;
    }
    float excl = __shfl_up(incl, 1, 16);
    if (sub == 0) excl = 1.0f;

    __syncthreads();   // sbuf (coords) fully consumed; reuse for weights

    // ---- weights (into LDS for coalesced store) + composite partials ----
    float acc[8];
    #pragma unroll
    for (int k = 0; k < 8; ++k) acc[k] = 0.0f;
    float t = excl;          // t == trans[6*sub + i] at top of iteration i
    float tauc = 0.0f;
    float* wl = sbuf + r * NI + 6 * sub;
    #pragma unroll
    for (int i = 0; i < 6; ++i) {
        float w = a[i] * t;
        if (i < 5 || sub < 15) wl[i] = w;            // weights -> LDS
        float dn1 = (i < 5) ? d[i+1] : d6;
        float dm  = 0.5f * (d[i] + dn1);
        float cmx = 0.5f * (c[3*i+0] + ((i < 5) ? c[3*i+3] : cn0));
        float cmy = 0.5f * (c[3*i+1] + ((i < 5) ? c[3*i+4] : cn1));
        float cmz = 0.5f * (c[3*i+2] + ((i < 5) ? c[3*i+5] : cn2));
        float pmx = 0.5f * (p[3*i+0] + ((i < 5) ? p[3*i+3] : pn0));
        float pmy = 0.5f * (p[3*i+1] + ((i < 5) ? p[3*i+4] : pn1));
        float pmz = 0.5f * (p[3*i+2] + ((i < 5) ? p[3*i+5] : pn2));
        acc[0] += w * cmx;  acc[1] += w * cmy;  acc[2] += w * cmz;
        acc[3] += w * pmx;  acc[4] += w * pmy;  acc[5] += w * pmz;
        acc[6] += w * dm;   acc[7] += w;
        if (i == 4) tauc = t;      // lane sub==15, i==4: t == trans[94] == tau
        t *= f[i];
    }
    float tau = __shfl(tauc, (lane & 48) | 15, 64);

    // ---- reduce 8 accumulators across the 16-lane group (4 butterfly steps) ----
    #pragma unroll
    for (int k = 0; k < 8; ++k) {
        #pragma unroll
        for (int off = 1; off < 16; off <<= 1)
            acc[k] += __shfl_xor(acc[k], off, 64);
    }

    if (sub == 0) {
        float add = (wbp != nullptr && wbp[0] != 0) ? (1.0f - acc[7]) : 0.0f;
        size_t rb = (size_t)OFF_RGB + (size_t)g * 3;
        out[rb + 0] = acc[0] + add;
        out[rb + 1] = acc[1] + add;
        out[rb + 2] = acc[2] + add;
        size_t pb = (size_t)OFF_PT + (size_t)g * 3;
        out[pb + 0] = acc[3];
        out[pb + 1] = acc[4];
        out[pb + 2] = acc[5];
        float cd = acc[6];
        if (cd != cd) cd = __int_as_float(0x7f800000);   // nan_to_num -> +inf
        float dmin = __uint_as_float(mm[0]);
        float dmax = __uint_as_float(~mm[1]);
        cd = fminf(fmaxf(cd, dmin), dmax);               // jnp.clip(global min/max)
        out[OFF_DEPTH + g] = cd;
        out[OFF_TAU + g]   = tau;
    }

    // ---- coalesced weights store: 16 rays x 95 = 1520 floats = 380 float4 ----
    __syncthreads();
    {
        float4* o4 = (float4*)(out + OFF_W + (size_t)blockIdx.x * (16 * NI));
        const float4* w4 = (const float4*)sbuf;
        o4[tid] = w4[tid];
        if (tid < 124) o4[256 + tid] = w4[256 + tid];
    }
}

extern "C" void kernel_launch(void* const* d_in, const int* in_sizes, int n_in,
                              void* d_out, int out_size, void* d_ws, size_t ws_size,
                              hipStream_t stream) {
    const float* colors = (const float*)d_in[0];
    const float* dens   = (const float*)d_in[1];
    const float* deps   = (const float*)d_in[2];
    const float* coords = (const float*)d_in[3];
    const int*   wb     = (n_in > 4) ? (const int*)d_in[4] : nullptr;
    float* out = (float*)d_out;
    unsigned* mm = (unsigned*)d_ws;

    // Both slots init 0xFFFFFFFF (min slot: uint-max; max slot stores ~bits).
    hipMemsetAsync(mm, 0xFF, 8, stream);
    depth_minmax_sorted<<<NRAYS / 256, 256, 0, stream>>>(deps, mm);
    raymarch<<<NRAYS / 16, 256, 0, stream>>>(colors, dens, deps, coords, wb, mm, out);
}

// Round 4
// 238.538 us; speedup vs baseline: 1.0358x; 1.0358x over previous
//
#include <hip/hip_runtime.h>

// Problem constants: B=4, R=16384, S=96
#define NRAYS 65536
#define NS    96
#define NI    95

// Output layout (FP32, outputs concatenated flat in return order):
//   composite_rgb   : [0,        196608)
//   composite_depth : [196608,   262144)
//   weights         : [262144,   6488064)
//   composite_point : [6488064,  6684672)
//   tau             : [6684672,  6750208)
#define OFF_RGB   0
#define OFF_DEPTH 196608
#define OFF_W     262144
#define OFF_PT    6488064
#define OFF_TAU   6684672

// ---------------------------------------------------------------------------
// Global depth min/max. depths are jnp.sort()ed along the sample axis by
// construction, so global min = min over rays of sample 0, global max = max
// over rays of sample 95. Max encoded as atomicMin of ~bits (depths >= 0),
// so both ws slots init 0xFFFFFFFF -> single 8-byte memset.
// ---------------------------------------------------------------------------
__global__ void depth_minmax_sorted(const float* __restrict__ deps, unsigned* ws) {
    const int t = blockIdx.x * blockDim.x + threadIdx.x;   // grid covers exactly NRAYS
    float lo = deps[(size_t)t * NS];
    float hi = deps[(size_t)t * NS + (NS - 1)];
    #pragma unroll
    for (int off = 32; off; off >>= 1) {
        lo = fminf(lo, __shfl_xor(lo, off, 64));
        hi = fmaxf(hi, __shfl_xor(hi, off, 64));
    }
    if ((threadIdx.x & 63) == 0) {
        atomicMin(&ws[0], __float_as_uint(lo));
        atomicMin(&ws[1], ~__float_as_uint(hi));   // max via inverted-bit min
    }
}

__device__ __forceinline__ float softplus_fast(float x) {
    // softplus = max(x,0) + log(1 + exp(-|x|)); __logf/__expf are single
    // v_log/v_exp instrs (~1e-6 rel err; tolerance headroom ~6x).
    return fmaxf(x, 0.0f) + __logf(1.0f + __expf(-fabsf(x)));
}

// ---------------------------------------------------------------------------
// R4: concurrency-first. R1-R3 all landed at 74-90 us with NO saturated pipe
// (VALU 12-14%, HBM <28%) -> latency/MLP-bound. Changes:
//  * ZERO __syncthreads: LDS staging is wave-private (each wave stages its
//    own 4 rays into its own 4608 B region; in-wave DS FIFO ordering +
//    compiler lgkmcnt waits give correctness without barriers).
//  * ALL global loads issued in one burst up front (~10 KB/wave in flight),
//    fully coalesced (float4/float2 streams); LDS region reused 3x:
//    d+n -> colors -> coords. Neighbor samples read from LDS (no shuffles).
//  * Weights revert to direct dword scatter (R1/R2-proven WRITE ~= 27 MB;
//    R3's LDS-staged float4 copy tripled WRITE_SIZE -> +11 us).
// Value path identical to verified R1-R3.
// ---------------------------------------------------------------------------
__launch_bounds__(256, 5)
__global__ void raymarch(const float* __restrict__ colors,
                         const float* __restrict__ dens,
                         const float* __restrict__ deps,
                         const float* __restrict__ coords,
                         const int* __restrict__ wbp,
                         const unsigned* __restrict__ mm,
                         float* __restrict__ out) {
    __shared__ float sbuf[4 * 1152];   // 18432 B: one 1152-float region per wave

    const int tid  = threadIdx.x;
    const int lane = tid & 63;
    const int wv   = tid >> 6;                    // wave in block (0..3)
    const int sub  = lane & 15;                   // position within ray group
    const int r4   = lane >> 4;                   // ray within wave (0..3)
    const int g    = blockIdx.x * 16 + wv * 4 + r4;   // global ray id

    // ---- issue ALL global loads up front (max MLP), fully coalesced ----
    const size_t rb0 = (size_t)blockIdx.x * 16 + wv * 4;  // first ray of wave
    const float2* dg2 = (const float2*)(deps + rb0 * NS);
    const float2* ng2 = (const float2*)(dens + rb0 * NS);
    float2 dr[3], nr[3];
    #pragma unroll
    for (int k = 0; k < 3; ++k) dr[k] = dg2[lane + 64 * k];   // 384 floats
    #pragma unroll
    for (int k = 0; k < 3; ++k) nr[k] = ng2[lane + 64 * k];
    const float4* cg4 = (const float4*)(colors + rb0 * NS * 3);
    const float4* pg4 = (const float4*)(coords + rb0 * NS * 3);
    float4 cr[4], pr[4];
    #pragma unroll
    for (int k = 0; k < 4; ++k) cr[k] = cg4[lane + 64 * k];   // 1024 floats
    float2 crt = ((const float2*)(colors + rb0 * NS * 3 + 1024))[lane];  // +128
    #pragma unroll
    for (int k = 0; k < 4; ++k) pr[k] = pg4[lane + 64 * k];
    float2 prt = ((const float2*)(coords + rb0 * NS * 3 + 1024))[lane];

    float* wreg = sbuf + wv * 1152;    // this wave's private LDS region

    // ---- phase A: stage d+n (wave-private, no barrier), read slices ----
    {
        float2* s2 = (float2*)wreg;
        #pragma unroll
        for (int k = 0; k < 3; ++k) s2[lane + 64 * k] = dr[k];        // d: [0,384)
        #pragma unroll
        for (int k = 0; k < 3; ++k) s2[192 + lane + 64 * k] = nr[k];  // n: [384,768)
    }
    float d[6], n[6], d6, n6;
    {
        const float2* qd = (const float2*)(wreg + r4 * 96 + 6 * sub);
        const float2* qn = (const float2*)(wreg + 384 + r4 * 96 + 6 * sub);
        #pragma unroll
        for (int j = 0; j < 3; ++j) { float2 v = qd[j]; d[2*j] = v.x; d[2*j+1] = v.y; }
        #pragma unroll
        for (int j = 0; j < 3; ++j) { float2 v = qn[j]; n[2*j] = v.x; n[2*j+1] = v.y; }
        const int noff = (sub < 15) ? 6 * (sub + 1) : 0;   // dummy for sub 15
        d6 = wreg[r4 * 96 + noff];
        n6 = wreg[384 + r4 * 96 + noff];
    }

    // ---- phase B: stage colors into the SAME region, read slices ----
    float4* s4 = (float4*)wreg;
    #pragma unroll
    for (int k = 0; k < 4; ++k) s4[lane + 64 * k] = cr[k];
    ((float2*)wreg)[512 + lane] = crt;                     // floats [1024,1152)
    float c[18], cn0, cn1, cn2;
    {
        const float2* q = (const float2*)(wreg + r4 * 288 + 18 * sub);
        #pragma unroll
        for (int j = 0; j < 9; ++j) { float2 v = q[j]; c[2*j] = v.x; c[2*j+1] = v.y; }
        const int noff = (sub < 15) ? 18 * (sub + 1) : 0;
        cn0 = wreg[r4 * 288 + noff + 0];
        cn1 = wreg[r4 * 288 + noff + 1];
        cn2 = wreg[r4 * 288 + noff + 2];
    }

    // ---- phase C: stage coords into the SAME region, read slices ----
    #pragma unroll
    for (int k = 0; k < 4; ++k) s4[lane + 64 * k] = pr[k];
    ((float2*)wreg)[512 + lane] = prt;
    float p[18], pn0, pn1, pn2;
    {
        const float2* q = (const float2*)(wreg + r4 * 288 + 18 * sub);
        #pragma unroll
        for (int j = 0; j < 9; ++j) { float2 v = q[j]; p[2*j] = v.x; p[2*j+1] = v.y; }
        const int noff = (sub < 15) ? 18 * (sub + 1) : 0;
        pn0 = wreg[r4 * 288 + noff + 0];
        pn1 = wreg[r4 * 288 + noff + 1];
        pn2 = wreg[r4 * 288 + noff + 2];
    }

    // ---- per-interval alpha / transmittance factor (interval 95 invalid) ----
    float a[6], f[6];
    #pragma unroll
    for (int i = 0; i < 6; ++i) {
        float dn1 = (i < 5) ? d[i+1] : d6;
        float nn1 = (i < 5) ? n[i+1] : n6;
        float E = __expf(-softplus_fast(0.5f * (n[i] + nn1)) * (dn1 - d[i]));
        const bool valid = (i < 5) || (sub < 15);    // compile-time except i==5
        a[i] = valid ? (1.0f - E) : 0.0f;
        f[i] = valid ? (E + 1e-10f) : 1.0f;
    }

    // ---- inclusive scan of per-lane factor product over the 16-lane group ----
    float incl = ((f[0] * f[1]) * (f[2] * f[3])) * (f[4] * f[5]);
    #pragma unroll
    for (int off = 1; off < 16; off <<= 1) {
        float t = __shfl_up(incl, off, 16);
        if (sub >= off) incl *= t;
    }
    float excl = __shfl_up(incl, 1, 16);
    if (sub == 0) excl = 1.0f;

    // ---- weights (direct scatter store, L2-merged) + composite partials ----
    float acc[8];
    #pragma unroll
    for (int k = 0; k < 8; ++k) acc[k] = 0.0f;
    float t = excl;          // t == trans[6*sub + i] at top of iteration i
    float tauc = 0.0f;
    const size_t wb = (size_t)OFF_W + (size_t)g * NI + 6 * sub;
    #pragma unroll
    for (int i = 0; i < 6; ++i) {
        float w = a[i] * t;
        if (i < 5 || sub < 15) out[wb + i] = w;      // weights output
        float dn1 = (i < 5) ? d[i+1] : d6;
        float dm  = 0.5f * (d[i] + dn1);
        float cmx = 0.5f * (c[3*i+0] + ((i < 5) ? c[3*i+3] : cn0));
        float cmy = 0.5f * (c[3*i+1] + ((i < 5) ? c[3*i+4] : cn1));
        float cmz = 0.5f * (c[3*i+2] + ((i < 5) ? c[3*i+5] : cn2));
        float pmx = 0.5f * (p[3*i+0] + ((i < 5) ? p[3*i+3] : pn0));
        float pmy = 0.5f * (p[3*i+1] + ((i < 5) ? p[3*i+4] : pn1));
        float pmz = 0.5f * (p[3*i+2] + ((i < 5) ? p[3*i+5] : pn2));
        acc[0] += w * cmx;  acc[1] += w * cmy;  acc[2] += w * cmz;
        acc[3] += w * pmx;  acc[4] += w * pmy;  acc[5] += w * pmz;
        acc[6] += w * dm;   acc[7] += w;
        if (i == 4) tauc = t;      // lane sub==15, i==4: t == trans[94] == tau
        t *= f[i];
    }
    float tau = __shfl(tauc, (lane & 48) | 15, 64);

    // ---- reduce 8 accumulators across the 16-lane group (4 butterfly steps) ----
    #pragma unroll
    for (int k = 0; k < 8; ++k) {
        #pragma unroll
        for (int off = 1; off < 16; off <<= 1)
            acc[k] += __shfl_xor(acc[k], off, 64);
    }

    if (sub == 0) {
        float add = (wbp != nullptr && wbp[0] != 0) ? (1.0f - acc[7]) : 0.0f;
        size_t rb = (size_t)OFF_RGB + (size_t)g * 3;
        out[rb + 0] = acc[0] + add;
        out[rb + 1] = acc[1] + add;
        out[rb + 2] = acc[2] + add;
        size_t pb = (size_t)OFF_PT + (size_t)g * 3;
        out[pb + 0] = acc[3];
        out[pb + 1] = acc[4];
        out[pb + 2] = acc[5];
        float cd = acc[6];
        if (cd != cd) cd = __int_as_float(0x7f800000);   // nan_to_num -> +inf
        float dmin = __uint_as_float(mm[0]);
        float dmax = __uint_as_float(~mm[1]);
        cd = fminf(fmaxf(cd, dmin), dmax);               // jnp.clip(global min/max)
        out[OFF_DEPTH + g] = cd;
        out[OFF_TAU + g]   = tau;
    }
}

extern "C" void kernel_launch(void* const* d_in, const int* in_sizes, int n_in,
                              void* d_out, int out_size, void* d_ws, size_t ws_size,
                              hipStream_t stream) {
    const float* colors = (const float*)d_in[0];
    const float* dens   = (const float*)d_in[1];
    const float* deps   = (const float*)d_in[2];
    const float* coords = (const float*)d_in[3];
    const int*   wb     = (n_in > 4) ? (const int*)d_in[4] : nullptr;
    float* out = (float*)d_out;
    unsigned* mm = (unsigned*)d_ws;

    // Both slots init 0xFFFFFFFF (min slot: uint-max; max slot stores ~bits).
    hipMemsetAsync(mm, 0xFF, 8, stream);
    depth_minmax_sorted<<<NRAYS / 256, 256, 0, stream>>>(deps, mm);
    raymarch<<<NRAYS / 16, 256, 0, stream>>>(colors, dens, deps, coords, wb, mm, out);
}